// Round 3
// baseline (214.138 us; speedup 1.0000x reference)
//
#include <hip/hip_runtime.h>
#include <math.h>

#define N_ROWS 262144
#define D 128
#define C 64
#define CD (C * D)
#define BLOCKS 1024
#define THREADS 512
#define WAVES 8
#define ROWS_PER_BLOCK (N_ROWS / BLOCKS)        // 256
#define ROWS_PER_WAVE (ROWS_PER_BLOCK / WAVES)  // 32
#define ITERS (ROWS_PER_WAVE / 4)               // 8
#define PF 3                                    // prefetch depth

// replica slot (floats): [0,CD) sums | [CD,CD+C) cnt | [CD+C,CD+2C) sq | [CD+2C] ce
#define SLOT 8448

__global__ __launch_bounds__(THREADS, 8) void proto_main(
    const float* __restrict__ emb, const float* __restrict__ logits,
    const int* __restrict__ labels, float* __restrict__ ws, int rmask) {
  __shared__ float sSums[CD];
  __shared__ float sCnt[C];
  __shared__ float sSq[C];
  __shared__ float sCe;

  const int tid = threadIdx.x;
  for (int i = tid; i < CD; i += THREADS) sSums[i] = 0.f;
  if (tid < C) { sCnt[tid] = 0.f; sSq[tid] = 0.f; }
  if (tid == 0) sCe = 0.f;
  __syncthreads();

  const int wave = tid >> 6, lane = tid & 63;
  const int g = lane >> 4, lp = lane & 15;  // 4 groups of 16 lanes; group g owns one row
  float ce_acc = 0.f;
  const int rowBase = blockIdx.x * ROWS_PER_BLOCK + wave * ROWS_PER_WAVE + g;

  // ---- explicit PF-deep prefetch pipeline (all indices compile-time) ----
  float4 sEa[PF], sEb[PF], sT4[PF];
  int sLab[PF];
#pragma unroll
  for (int k = 0; k < PF; ++k) {
    const int row = rowBase + k * 4;
    const float* ep = emb + (size_t)row * D + lp * 8;
    sEa[k] = *(const float4*)ep;
    sEb[k] = *(const float4*)(ep + 4);
    sT4[k] = *(const float4*)(logits + (size_t)row * C + lp * 4);
    sLab[k] = labels[row];
  }

#pragma unroll
  for (int it = 0; it < ITERS; ++it) {
    const int s = it % PF;  // compile-time (full unroll)
    const float4 ea = sEa[s], eb = sEb[s], t4 = sT4[s];
    const int lab = sLab[s];

    // prefetch iteration it+PF into this stage
    if (it + PF < ITERS) {
      const int row = rowBase + (it + PF) * 4;
      const float* ep = emb + (size_t)row * D + lp * 8;
      sEa[s] = *(const float4*)ep;
      sEb[s] = *(const float4*)(ep + 4);
      sT4[s] = *(const float4*)(logits + (size_t)row * C + lp * 4);
      sLab[s] = labels[row];
    }

    // ---- L2 norm over the group's 16 lanes ----
    float ss = ea.x * ea.x + ea.y * ea.y + ea.z * ea.z + ea.w * ea.w +
               eb.x * eb.x + eb.y * eb.y + eb.z * eb.z + eb.w * eb.w;
    ss += __shfl_xor(ss, 1);
    ss += __shfl_xor(ss, 2);
    ss += __shfl_xor(ss, 4);
    ss += __shfl_xor(ss, 8);
    const float inv = 1.0f / fmaxf(sqrtf(ss), 1e-12f);

    // ---- cross-entropy ----
    float p = __expf(t4.x) + __expf(t4.y) + __expf(t4.z) + __expf(t4.w);
    float tl = 0.f;
    if ((lab >> 2) == lp) {
      const int k = lab & 3;
      tl = k == 0 ? t4.x : k == 1 ? t4.y : k == 2 ? t4.z : t4.w;
    }
    p += __shfl_xor(p, 1);  tl += __shfl_xor(tl, 1);
    p += __shfl_xor(p, 2);  tl += __shfl_xor(tl, 2);
    p += __shfl_xor(p, 4);  tl += __shfl_xor(tl, 4);
    p += __shfl_xor(p, 8);  tl += __shfl_xor(tl, 8);

    if (lp == 0) {
      ce_acc += __logf(p) - tl;
      atomicAdd(&sCnt[lab], 1.f);
      atomicAdd(&sSq[lab], ss * inv * inv);
    }

    // ---- class sums, transposed slot j*16+lp (16 banks/instr, order-free) ----
    const int cb = lab * D + lp;
    atomicAdd(&sSums[cb + 0],   ea.x * inv);
    atomicAdd(&sSums[cb + 16],  ea.y * inv);
    atomicAdd(&sSums[cb + 32],  ea.z * inv);
    atomicAdd(&sSums[cb + 48],  ea.w * inv);
    atomicAdd(&sSums[cb + 64],  eb.x * inv);
    atomicAdd(&sSums[cb + 80],  eb.y * inv);
    atomicAdd(&sSums[cb + 96],  eb.z * inv);
    atomicAdd(&sSums[cb + 112], eb.w * inv);
  }
  if (lp == 0) atomicAdd(&sCe, ce_acc);
  __syncthreads();

  // ---- flush block partials into one of R replica accumulators ----
  float* rep = ws + (size_t)(blockIdx.x & rmask) * SLOT;
  const int rot = (blockIdx.x * 997) & (CD - 1);
  for (int i = tid; i < CD; i += THREADS) {
    const int j = (i + rot) & (CD - 1);
    atomicAdd(&rep[j], sSums[j]);
  }
  if (tid < C) atomicAdd(&rep[CD + tid], sCnt[tid]);
  else if (tid < 2 * C) atomicAdd(&rep[CD + C + (tid - C)], sSq[tid - C]);
  else if (tid == 2 * C) atomicAdd(&rep[CD + 2 * C], sCe);
}

__global__ __launch_bounds__(128) void proto_class(const float* __restrict__ ws,
                                                   int nrep, float* __restrict__ res) {
  const int c = blockIdx.x, t = threadIdx.x;  // t = permuted dim slot in [0,128)
  float s = 0.f, n = 0.f, sq = 0.f;
  for (int r = 0; r < nrep; ++r) {
    const float* rep = ws + (size_t)r * SLOT;
    s += rep[c * D + t];
    n += rep[CD + c];
    sq += rep[CD + C + c];
  }
  const float safe = fmaxf(n, 1.f);
  const float mu = s / safe;
  float msq = mu * mu;
#pragma unroll
  for (int off = 1; off < 64; off <<= 1) msq += __shfl_xor(msq, off);
  __shared__ float sP[2];
  if ((t & 63) == 0) sP[t >> 6] = msq;
  __syncthreads();
  if (t == 0) {
    const float m2 = sP[0] + sP[1];
    const float ssd = sq - n * m2;
    const bool valid = n > 1.f;
    res[c] = valid ? ssd / safe : 0.f;
    res[C + c] = valid ? 1.f : 0.f;
  }
}

__global__ __launch_bounds__(64) void proto_final(const float* __restrict__ ws,
                                                  const float* __restrict__ res,
                                                  int nrep, float* __restrict__ out) {
  const int t = threadIdx.x;
  float pc = res[t], v = res[C + t];
#pragma unroll
  for (int off = 1; off < 64; off <<= 1) { pc += __shfl_xor(pc, off); v += __shfl_xor(v, off); }
  if (t == 0) {
    float ce = 0.f;
    for (int r = 0; r < nrep; ++r) ce += ws[(size_t)r * SLOT + CD + 2 * C];
    ce /= (float)N_ROWS;
    out[0] = 0.5f * ce + 0.5f * (pc / fmaxf(v, 1.f));
  }
}

extern "C" void kernel_launch(void* const* d_in, const int* in_sizes, int n_in,
                              void* d_out, int out_size, void* d_ws, size_t ws_size,
                              hipStream_t stream) {
  const float* emb = (const float*)d_in[0];
  const float* logits = (const float*)d_in[1];
  const int* labels = (const int*)d_in[2];
  float* ws = (float*)d_ws;
  float* out = (float*)d_out;

  int R = 16;
  while (R > 1 && (size_t)(R * SLOT + 2 * C) * sizeof(float) > ws_size) R >>= 1;
  float* res = ws + (size_t)R * SLOT;

  hipMemsetAsync(ws, 0, (size_t)R * SLOT * sizeof(float), stream);
  proto_main<<<BLOCKS, THREADS, 0, stream>>>(emb, logits, labels, ws, R - 1);
  proto_class<<<C, 128, 0, stream>>>(ws, R, res);
  proto_final<<<1, 64, 0, stream>>>(ws, res, R, out);
}

// Round 4
// 116.088 us; speedup vs baseline: 1.8446x; 1.8446x over previous
//
#include <hip/hip_runtime.h>
#include <math.h>

#define N_ROWS 262144
#define D 128
#define C 64
#define SLOT 8320            // 8192 class-dim sums + 64 cnt + 64 sq
#define CE_BLOCKS 2048
#define PROTO_BLOCKS 1024
#define RPB 256              // rows per proto block
#define CHUNK 64
#define NCH (RPB / CHUNK)    // 4

// ---------------- cross-entropy: no atomics, plain per-block store ----------
__global__ __launch_bounds__(256, 8) void ce_kernel(
    const float* __restrict__ logits, const int* __restrict__ labels,
    float* __restrict__ ce_out) {
  __shared__ float sCe[4];
  const int tid = threadIdx.x;
  const int wave = tid >> 6, lane = tid & 63;
  const int g = lane >> 4, lp = lane & 15;
  const int rowBase = blockIdx.x * 128 + wave * 32 + g;
  float ce_acc = 0.f;

  float4 tA, tB;
  int labA = 0, labB = 0;
  tA = *(const float4*)(logits + (size_t)rowBase * C + lp * 4);
  labA = labels[rowBase];
  tB = tA;

#pragma unroll
  for (int it = 0; it < 8; ++it) {
    const float4 t4 = (it & 1) ? tB : tA;   // constant-folds after unroll
    const int lab = (it & 1) ? labB : labA;
    if (it + 1 < 8) {                        // prefetch next row-quad
      const int row = rowBase + (it + 1) * 4;
      if (it & 1) {
        tA = *(const float4*)(logits + (size_t)row * C + lp * 4);
        labA = labels[row];
      } else {
        tB = *(const float4*)(logits + (size_t)row * C + lp * 4);
        labB = labels[row];
      }
    }
    float p = __expf(t4.x) + __expf(t4.y) + __expf(t4.z) + __expf(t4.w);
    float tl = 0.f;
    if ((lab >> 2) == lp) {
      const int k = lab & 3;
      tl = k == 0 ? t4.x : k == 1 ? t4.y : k == 2 ? t4.z : t4.w;
    }
    p += __shfl_xor(p, 1);  tl += __shfl_xor(tl, 1);
    p += __shfl_xor(p, 2);  tl += __shfl_xor(tl, 2);
    p += __shfl_xor(p, 4);  tl += __shfl_xor(tl, 4);
    p += __shfl_xor(p, 8);  tl += __shfl_xor(tl, 8);
    if (lp == 0) ce_acc += __logf(p) - tl;
  }
  ce_acc += __shfl_xor(ce_acc, 16);
  ce_acc += __shfl_xor(ce_acc, 32);
  if (lane == 0) sCe[wave] = ce_acc;
  __syncthreads();
  if (tid == 0) ce_out[blockIdx.x] = sCe[0] + sCe[1] + sCe[2] + sCe[3];
}

// ---------------- proto: chunked LDS staging, register class-accumulators ---
__global__ __launch_bounds__(512, 4) void proto_kernel(
    const float* __restrict__ emb, const int* __restrict__ labels,
    float* __restrict__ ws, int rmask) {
  __shared__ float sE[CHUNK][D];    // 32 KB raw emb chunk
  __shared__ float sP[CHUNK][8];    // per-row norm partials
  __shared__ float sInv[CHUNK];
  __shared__ float sSsq[CHUNK];
  __shared__ int sLab[CHUNK];

  const int tid = threadIdx.x;
  const int wave = tid >> 6, lane = tid & 63;
  const int r0 = tid >> 3, p0 = tid & 7;    // thread stages 16 floats of row r0
  const int base = blockIdx.x * RPB;

  float2 acc[8];                    // wave owns classes [8*wave, 8*wave+8)
  float cntA[8], sqA[8];            // lane owns dims (2*lane, 2*lane+1)
#pragma unroll
  for (int q = 0; q < 8; ++q) { acc[q].x = 0.f; acc[q].y = 0.f; cntA[q] = 0.f; sqA[q] = 0.f; }

  const float* g0 = emb + (size_t)(base + r0) * D + p0 * 16;
  float4 a0 = *(const float4*)(g0 + 0);
  float4 a1 = *(const float4*)(g0 + 4);
  float4 a2 = *(const float4*)(g0 + 8);
  float4 a3 = *(const float4*)(g0 + 12);
  int labRA = (tid < CHUNK) ? labels[base + tid] : 0;
  float4 b0 = a0, b1 = a1, b2 = a2, b3 = a3;
  int labRB = 0;

#pragma unroll
  for (int ch = 0; ch < NCH; ++ch) {
    const float4 e0 = (ch & 1) ? b0 : a0;   // constant-folds after unroll
    const float4 e1 = (ch & 1) ? b1 : a1;
    const float4 e2 = (ch & 1) ? b2 : a2;
    const float4 e3 = (ch & 1) ? b3 : a3;
    const int labStage = (ch & 1) ? labRB : labRA;

    float* dst = &sE[r0][p0 * 16];
    *(float4*)(dst + 0) = e0;
    *(float4*)(dst + 4) = e1;
    *(float4*)(dst + 8) = e2;
    *(float4*)(dst + 12) = e3;
    sP[r0][p0] = e0.x * e0.x + e0.y * e0.y + e0.z * e0.z + e0.w * e0.w +
                 e1.x * e1.x + e1.y * e1.y + e1.z * e1.z + e1.w * e1.w +
                 e2.x * e2.x + e2.y * e2.y + e2.z * e2.z + e2.w * e2.w +
                 e3.x * e3.x + e3.y * e3.y + e3.z * e3.z + e3.w * e3.w;
    if (tid < CHUNK) sLab[tid] = labStage;
    __syncthreads();

    // issue next chunk's global loads NOW (latency hides under norm+accum)
    if (ch + 1 < NCH) {
      const float* g2 = emb + (size_t)(base + (ch + 1) * CHUNK + r0) * D + p0 * 16;
      if (ch & 1) {
        a0 = *(const float4*)(g2 + 0);  a1 = *(const float4*)(g2 + 4);
        a2 = *(const float4*)(g2 + 8);  a3 = *(const float4*)(g2 + 12);
        if (tid < CHUNK) labRA = labels[base + (ch + 1) * CHUNK + tid];
      } else {
        b0 = *(const float4*)(g2 + 0);  b1 = *(const float4*)(g2 + 4);
        b2 = *(const float4*)(g2 + 8);  b3 = *(const float4*)(g2 + 12);
        if (tid < CHUNK) labRB = labels[base + (ch + 1) * CHUNK + tid];
      }
    }

    if (wave == 0) {  // finish norms: lane = row
      const float* pp = sP[lane];
      const float s = pp[0] + pp[1] + pp[2] + pp[3] + pp[4] + pp[5] + pp[6] + pp[7];
      const float invv = 1.0f / fmaxf(sqrtf(s), 1e-12f);
      sInv[lane] = invv;
      sSsq[lane] = s * invv * invv;
    }
    __syncthreads();

    // accumulate: ballot-walk only this wave's rows (~8 of 64)
    const int myLab = sLab[lane];
    unsigned long long msk = __ballot((myLab >> 3) == wave);
    while (msk) {
      const int r = (int)__builtin_ctzll(msk);
      msk &= msk - 1;
      const int lab7 = __shfl(myLab, r) & 7;
      const float invv = sInv[r];
      const float ssq = sSsq[r];
      const float2 e = *(const float2*)&sE[r][lane * 2];
      const float zx = e.x * invv, zy = e.y * invv;
#pragma unroll
      for (int q = 0; q < 8; ++q) {
        const float msel = (q == lab7) ? 1.f : 0.f;
        acc[q].x += msel * zx;
        acc[q].y += msel * zy;
        cntA[q] += msel;
        sqA[q] += msel * ssq;
      }
    }
    __syncthreads();
  }

  // flush once per block into replica (<=16-way same-address serialization)
  float* rep = ws + (size_t)(blockIdx.x & rmask) * SLOT;
#pragma unroll
  for (int q = 0; q < 8; ++q) {
    const int c = wave * 8 + q;
    atomicAdd(&rep[c * D + lane * 2], acc[q].x);
    atomicAdd(&rep[c * D + lane * 2 + 1], acc[q].y);
  }
  if (lane == 0) {
#pragma unroll
    for (int q = 0; q < 8; ++q) {
      atomicAdd(&rep[8192 + wave * 8 + q], cntA[q]);
      atomicAdd(&rep[8256 + wave * 8 + q], sqA[q]);
    }
  }
}

// ---------------- sum R replicas -> fin[8320] --------------------------------
__global__ __launch_bounds__(256) void reduce_kernel(
    const float* __restrict__ ws, int R, float* __restrict__ fin) {
  __shared__ float sRed[4][64];
  const int tid = threadIdx.x;
  const int soff = tid & 63, rq = tid >> 6;
  const int s = blockIdx.x * 64 + soff;
  float a = 0.f;
  for (int r = rq; r < R; r += 4) a += ws[(size_t)r * SLOT + s];
  sRed[rq][soff] = a;
  __syncthreads();
  if (tid < 64) fin[blockIdx.x * 64 + tid] =
      sRed[0][tid] + sRed[1][tid] + sRed[2][tid] + sRed[3][tid];
}

// ---------------- per-class stats -------------------------------------------
__global__ __launch_bounds__(128) void class_kernel(
    const float* __restrict__ fin, float* __restrict__ res) {
  __shared__ float sM[2];
  const int c = blockIdx.x, t = threadIdx.x;
  const float n = fin[8192 + c];
  const float safe = fmaxf(n, 1.f);
  const float mu = fin[c * D + t] / safe;
  float msq = mu * mu;
#pragma unroll
  for (int off = 1; off < 64; off <<= 1) msq += __shfl_xor(msq, off);
  if ((t & 63) == 0) sM[t >> 6] = msq;
  __syncthreads();
  if (t == 0) {
    const float sq = fin[8256 + c];
    const float ssd = sq - n * (sM[0] + sM[1]);
    const bool valid = n > 1.f;
    res[c] = valid ? ssd / safe : 0.f;
    res[C + c] = valid ? 1.f : 0.f;
  }
}

// ---------------- final scalar ----------------------------------------------
__global__ __launch_bounds__(256) void final_kernel(
    const float* __restrict__ ceB, const float* __restrict__ res,
    float* __restrict__ out) {
  __shared__ float sv[4][3];
  const int tid = threadIdx.x, wave = tid >> 6, lane = tid & 63;
  float ce = 0.f;
  for (int i = tid; i < CE_BLOCKS; i += 256) ce += ceB[i];
  float pr = 0.f, nv = 0.f;
  if (wave == 0) { pr = res[lane]; nv = res[C + lane]; }
#pragma unroll
  for (int off = 1; off < 64; off <<= 1) {
    ce += __shfl_xor(ce, off);
    pr += __shfl_xor(pr, off);
    nv += __shfl_xor(nv, off);
  }
  if (lane == 0) { sv[wave][0] = ce; sv[wave][1] = pr; sv[wave][2] = nv; }
  __syncthreads();
  if (tid == 0) {
    const float c2 = sv[0][0] + sv[1][0] + sv[2][0] + sv[3][0];
    const float p2 = sv[0][1] + sv[1][1] + sv[2][1] + sv[3][1];
    const float n2 = sv[0][2] + sv[1][2] + sv[2][2] + sv[3][2];
    out[0] = 0.5f * (c2 / (float)N_ROWS) + 0.5f * (p2 / fmaxf(n2, 1.f));
  }
}

extern "C" void kernel_launch(void* const* d_in, const int* in_sizes, int n_in,
                              void* d_out, int out_size, void* d_ws, size_t ws_size,
                              hipStream_t stream) {
  const float* emb = (const float*)d_in[0];
  const float* logits = (const float*)d_in[1];
  const int* labels = (const int*)d_in[2];
  float* ws = (float*)d_ws;
  float* out = (float*)d_out;

  int R = 64;
  while (R > 1 &&
         ((size_t)R * SLOT + CE_BLOCKS + SLOT + 2 * C) * sizeof(float) > ws_size)
    R >>= 1;
  float* ceB = ws + (size_t)R * SLOT;
  float* fin = ceB + CE_BLOCKS;
  float* res = fin + SLOT;

  hipMemsetAsync(ws, 0, (size_t)R * SLOT * sizeof(float), stream);
  ce_kernel<<<CE_BLOCKS, 256, 0, stream>>>(logits, labels, ceB);
  proto_kernel<<<PROTO_BLOCKS, 512, 0, stream>>>(emb, labels, ws, R - 1);
  reduce_kernel<<<SLOT / 64, 256, 0, stream>>>(ws, R, fin);
  class_kernel<<<C, 128, 0, stream>>>(fin, res);
  final_kernel<<<1, 256, 0, stream>>>(ceB, res, out);
}